// Round 1
// baseline (1108.277 us; speedup 1.0000x reference)
//
#include <hip/hip_runtime.h>
#include <math.h>

#define EPS_F 1e-6f

// ---------------- small kernels ----------------

// FF[i][j] = sum_k F[k][i]*F[k][j]   (F is 128x128 row-major)
__global__ void kff(const float* __restrict__ F, float* __restrict__ FF) {
    int i = blockIdx.x, j = threadIdx.x;
    float s = 0.f;
    for (int k = 0; k < 128; ++k) s += F[k*128 + i] * F[k*128 + j];
    FF[i*128 + j] = s;
}

// inv[0] = 1/(||FF||_F + eps)
__global__ void knorm(const float* __restrict__ FF, float* __restrict__ inv) {
    float s = 0.f;
    for (int idx = threadIdx.x; idx < 128*128; idx += 256) { float v = FF[idx]; s += v*v; }
    for (int o = 32; o > 0; o >>= 1) s += __shfl_down(s, o);
    __shared__ float wsum[4];
    int lane = threadIdx.x & 63, w = threadIdx.x >> 6;
    if (lane == 0) wsum[w] = s;
    __syncthreads();
    if (threadIdx.x == 0) inv[0] = 1.f / (sqrtf(wsum[0]+wsum[1]+wsum[2]+wsum[3]) + EPS_F);
}

// D[j] = gamma * Lambda_S[j]
__global__ void kdvec(const float* __restrict__ lam, const float* __restrict__ gam,
                      float* __restrict__ D, int n) {
    int i = blockIdx.x*blockDim.x + threadIdx.x;
    if (i < n) D[i] = gam[0]*lam[i];
}

// ---------------- GEMM (M fixed = 128) ----------------
// C[128][N] (+)= A[128][K] * op(B),  op(B)[k][n] = TRANSB ? B[n][K-major][k] : B[k][n]
// MODE 0: atomicAdd into C (C must be pre-zeroed; supports split-K via blockIdx.y)
// MODE 1: C = Yin + acc * (Dvec[col] * invn[0])   (single K chunk)
template<int BN, int TN, bool TRANSB, int MODE>
__global__ __launch_bounds__(256) void gemm128(
    const float* __restrict__ A, const float* __restrict__ B,
    float* __restrict__ C, const float* __restrict__ Yin,
    const float* __restrict__ Dvec, const float* __restrict__ invn,
    int N, int K, int kChunk)
{
    constexpr int BM = 128, BK = 16, TM = 8;
    constexpr int PAD = TRANSB ? 1 : 0;
    __shared__ float As[BK][BM];
    __shared__ float Bs[BK][BN + PAD];

    const int t = threadIdx.x;
    const int n0 = blockIdx.x * BN;
    const int k_beg = blockIdx.y * kChunk;
    const int k_end = k_beg + kChunk;

    constexpr int TCN = BN / TN;      // threads along N (=16)
    const int tr = t / TCN;           // 0..15  -> rows tr*8..+7
    const int tc = t % TCN;           // 0..15  -> cols tc*TN..

    float acc[TM][TN];
    #pragma unroll
    for (int i = 0; i < TM; ++i)
        #pragma unroll
        for (int j = 0; j < TN; ++j) acc[i][j] = 0.f;

    for (int k0 = k_beg; k0 < k_end; k0 += BK) {
        // --- A tile: As[kk][m] = A[m][k0+kk]; 128x16 = 512 float4 loads
        #pragma unroll
        for (int it = 0; it < 2; ++it) {
            int flat = t + it*256;
            int m = flat >> 2, k4 = flat & 3;
            float4 v = *(const float4*)&A[(size_t)m*K + k0 + k4*4];
            As[k4*4+0][m] = v.x; As[k4*4+1][m] = v.y;
            As[k4*4+2][m] = v.z; As[k4*4+3][m] = v.w;
        }
        // --- B tile
        if (!TRANSB) {
            constexpr int NV = BK*BN/4;
            #pragma unroll
            for (int it = 0; it < NV/256; ++it) {
                int flat = t + it*256;
                int kk = flat / (BN/4), n4 = flat % (BN/4);
                *(float4*)&Bs[kk][n4*4] =
                    *(const float4*)&B[(size_t)(k0+kk)*N + n0 + n4*4];
            }
        } else {
            constexpr int NV = BK*BN/4;
            #pragma unroll
            for (int it = 0; it < NV/256; ++it) {
                int flat = t + it*256;
                int n = flat / (BK/4), k4 = flat % (BK/4);
                float4 v = *(const float4*)&B[(size_t)(n0+n)*K + k0 + k4*4];
                Bs[k4*4+0][n] = v.x; Bs[k4*4+1][n] = v.y;
                Bs[k4*4+2][n] = v.z; Bs[k4*4+3][n] = v.w;
            }
        }
        __syncthreads();

        #pragma unroll
        for (int kk = 0; kk < BK; ++kk) {
            float a[TM], b[TN];
            #pragma unroll
            for (int i = 0; i < TM; i += 4)
                *(float4*)&a[i] = *(const float4*)&As[kk][tr*TM + i];
            if (!TRANSB) {
                #pragma unroll
                for (int j = 0; j < TN; j += 4)
                    *(float4*)&b[j] = *(const float4*)&Bs[kk][tc*TN + j];
            } else {
                #pragma unroll
                for (int j = 0; j < TN; ++j) b[j] = Bs[kk][tc*TN + j];
            }
            #pragma unroll
            for (int i = 0; i < TM; ++i)
                #pragma unroll
                for (int j = 0; j < TN; ++j)
                    acc[i][j] = fmaf(a[i], b[j], acc[i][j]);
        }
        __syncthreads();
    }

    if (MODE == 0) {
        #pragma unroll
        for (int i = 0; i < TM; ++i) {
            int row = tr*TM + i;
            #pragma unroll
            for (int j = 0; j < TN; ++j) {
                int col = n0 + tc*TN + j;
                atomicAdd(&C[(size_t)row*N + col], acc[i][j]);
            }
        }
    } else {
        float inv0 = invn[0];
        float sc[TN];
        #pragma unroll
        for (int j = 0; j < TN; ++j) sc[j] = Dvec[n0 + tc*TN + j] * inv0;
        #pragma unroll
        for (int i = 0; i < TM; ++i) {
            int row = tr*TM + i;
            #pragma unroll
            for (int j = 0; j < TN; ++j) {
                int col = n0 + tc*TN + j;
                C[(size_t)row*N + col] = Yin[(size_t)row*N + col] + acc[i][j]*sc[j];
            }
        }
    }
}

// ---------------- launch ----------------

extern "C" void kernel_launch(void* const* d_in, const int* in_sizes, int n_in,
                              void* d_out, int out_size, void* d_ws, size_t ws_size,
                              hipStream_t stream) {
    const float* X   = (const float*)d_in[0];   // 128 x 8192
    const float* F   = (const float*)d_in[1];   // 128 x 128
    const float* Q   = (const float*)d_in[2];   // 8192 x 8192
    const float* lam = (const float*)d_in[3];   // 8192
    const float* gam = (const float*)d_in[4];   // 1
    float* Z = (float*)d_out;                   // 128 x 8192 (f32)

    const int M = 128, N = 8192, K = 8192;

    char* ws = (char*)d_ws;
    float* FF  = (float*)(ws);                       // 64 KB
    float* inv = (float*)(ws + 65536);               // 4 B (pad 256)
    float* D   = (float*)(ws + 65792);               // 32 KB
    float* Y   = (float*)(ws + 131072);              // 4 MB
    float* RA  = (float*)(ws + 131072 + 4194304);    // 4 MB

    // A = g(F) pieces
    hipLaunchKernelGGL(kff,   dim3(128), dim3(128), 0, stream, F, FF);
    hipLaunchKernelGGL(knorm, dim3(1),   dim3(256), 0, stream, FF, inv);
    hipLaunchKernelGGL(kdvec, dim3(32),  dim3(256), 0, stream, lam, gam, D, N);

    // Y = X @ Q_S   (split-K=4, atomic accumulate)
    hipMemsetAsync(Y, 0, (size_t)M*N*sizeof(float), stream);
    hipLaunchKernelGGL((gemm128<128,8,false,0>), dim3(64,4), dim3(256), 0, stream,
                       X, Q, Y, nullptr, nullptr, nullptr, N, K, 2048);

    // Horner/Neumann: R <- Y + (D[j]*inv) * (FF @ R), 17 iterations.
    // Ping-pong: RA (ws) and RB (= d_out used as scratch). 17 iters -> result in RA.
    float* RB = Z;
    const int KT = 17;
    for (int it = 0; it < KT; ++it) {
        const float* in = (it == 0) ? Y : ((it & 1) ? RA : RB);
        float* outp = (it & 1) ? RB : RA;
        hipLaunchKernelGGL((gemm128<64,4,false,1>), dim3(128,1), dim3(256), 0, stream,
                           FF, in, outp, Y, D, inv, N, 128, 128);
    }

    // Z = RA @ Q_S^T  (split-K=4, atomic accumulate)
    hipMemsetAsync(Z, 0, (size_t)M*N*sizeof(float), stream);
    hipLaunchKernelGGL((gemm128<128,8,true,0>), dim3(64,4), dim3(256), 0, stream,
                       RA, Q, Z, nullptr, nullptr, nullptr, N, K, 2048);
}

// Round 2
// 393.319 us; speedup vs baseline: 2.8178x; 2.8178x over previous
//
#include <hip/hip_runtime.h>
#include <math.h>

#define EPS_F 1e-6f

typedef __attribute__((ext_vector_type(8))) short short8;
typedef __attribute__((ext_vector_type(4))) float f32x4;

static __device__ __forceinline__ unsigned short f2bf(float f) {
    unsigned u = __float_as_uint(f);
    u += 0x7fff + ((u >> 16) & 1);          // round-to-nearest-even
    return (unsigned short)(u >> 16);
}

// ---------------- small kernels ----------------

__global__ void kff(const float* __restrict__ F, float* __restrict__ FF) {
    int i = blockIdx.x, j = threadIdx.x;
    float s = 0.f;
    for (int k = 0; k < 128; ++k) s += F[k*128 + i] * F[k*128 + j];
    FF[i*128 + j] = s;
}

__global__ void knorm(const float* __restrict__ FF, float* __restrict__ inv) {
    float s = 0.f;
    for (int idx = threadIdx.x; idx < 128*128; idx += 256) { float v = FF[idx]; s += v*v; }
    for (int o = 32; o > 0; o >>= 1) s += __shfl_down(s, o);
    __shared__ float wsum[4];
    int lane = threadIdx.x & 63, w = threadIdx.x >> 6;
    if (lane == 0) wsum[w] = s;
    __syncthreads();
    if (threadIdx.x == 0) inv[0] = 1.f / (sqrtf(wsum[0]+wsum[1]+wsum[2]+wsum[3]) + EPS_F);
}

__global__ void kdvec(const float* __restrict__ lam, const float* __restrict__ gam,
                      float* __restrict__ D, int n) {
    int i = blockIdx.x*blockDim.x + threadIdx.x;
    if (i < n) D[i] = gam[0]*lam[i];
}

// ---------------- MFMA GEMM: C[128][N] += A[128][K] * op(B), bf16 inputs ----------------
// op(B)[k][n] = TRANSB ? B[n][k] : B[k][n].  C pre-zeroed, atomicAdd accumulate (split-K).
template<bool TRANSB>
__global__ __launch_bounds__(256) void gemm_mfma(
    const float* __restrict__ A, const float* __restrict__ B,
    float* __restrict__ C, int N, int K, int kChunk)
{
    constexpr int LDT = 40;                 // shorts per LDS row: 32 data + 8 pad (80 B)
    __shared__ short As[128 * LDT];
    __shared__ short Bs[128 * LDT];

    const int t    = threadIdx.x;
    const int lane = t & 63;
    const int w    = t >> 6;                // wave 0..3
    const int wm   = (w >> 1) * 64;         // wave quadrant row
    const int wn   = (w & 1)  * 64;         // wave quadrant col
    const int l16  = lane & 15;
    const int lq   = lane >> 4;             // 0..3
    const int n0   = blockIdx.x * 128;
    const int k_beg = blockIdx.y * kChunk;

    f32x4 acc[4][4];
    #pragma unroll
    for (int i = 0; i < 4; ++i)
        #pragma unroll
        for (int j = 0; j < 4; ++j) acc[i][j] = (f32x4){0.f,0.f,0.f,0.f};

    // staging indices (non-trans B): lane-coalesced n sweep
    const int bn = t & 127, bkh = t >> 7;   // n-col, k-half (0/1)

    for (int k0 = k_beg; k0 < k_beg + kChunk; k0 += 32) {
        // ---- A tile -> As[m][k] (k-contiguous, vector loads)
        #pragma unroll
        for (int i = 0; i < 4; ++i) {
            int flat = t + i*256;           // 0..1023
            int m = flat >> 3, k4 = flat & 7;
            float4 v = *(const float4*)&A[(size_t)m*K + k0 + k4*4];
            unsigned long long pk =
                  (unsigned long long)f2bf(v.x)
                | ((unsigned long long)f2bf(v.y) << 16)
                | ((unsigned long long)f2bf(v.z) << 32)
                | ((unsigned long long)f2bf(v.w) << 48);
            *(unsigned long long*)&As[m*LDT + k4*4] = pk;
        }
        // ---- B tile -> Bs[n][k]
        if (TRANSB) {
            #pragma unroll
            for (int i = 0; i < 4; ++i) {
                int flat = t + i*256;
                int n = flat >> 3, k4 = flat & 7;
                float4 v = *(const float4*)&B[(size_t)(n0+n)*K + k0 + k4*4];
                unsigned long long pk =
                      (unsigned long long)f2bf(v.x)
                    | ((unsigned long long)f2bf(v.y) << 16)
                    | ((unsigned long long)f2bf(v.z) << 32)
                    | ((unsigned long long)f2bf(v.w) << 48);
                *(unsigned long long*)&Bs[n*LDT + k4*4] = pk;
            }
        } else {
            // transpose during staging: scalar f32 loads, coalesced across the 128-lane n sweep
            float vv[16];
            #pragma unroll
            for (int j = 0; j < 16; ++j)
                vv[j] = B[(size_t)(k0 + bkh*16 + j)*N + n0 + bn];
            short8 p0, p1;
            #pragma unroll
            for (int j = 0; j < 8; ++j) { p0[j] = (short)f2bf(vv[j]); p1[j] = (short)f2bf(vv[j+8]); }
            *(short8*)&Bs[bn*LDT + bkh*16    ] = p0;
            *(short8*)&Bs[bn*LDT + bkh*16 + 8] = p1;
        }
        __syncthreads();

        short8 a[4], b[4];
        #pragma unroll
        for (int mt = 0; mt < 4; ++mt)
            a[mt] = *(const short8*)&As[(wm + mt*16 + l16)*LDT + lq*8];
        #pragma unroll
        for (int nt = 0; nt < 4; ++nt)
            b[nt] = *(const short8*)&Bs[(wn + nt*16 + l16)*LDT + lq*8];
        #pragma unroll
        for (int mt = 0; mt < 4; ++mt)
            #pragma unroll
            for (int nt = 0; nt < 4; ++nt)
                acc[mt][nt] = __builtin_amdgcn_mfma_f32_16x16x32_bf16(a[mt], b[nt], acc[mt][nt], 0, 0, 0);
        __syncthreads();
    }

    // ---- epilogue: atomic accumulate (split-K)
    #pragma unroll
    for (int mt = 0; mt < 4; ++mt)
        #pragma unroll
        for (int nt = 0; nt < 4; ++nt)
            #pragma unroll
            for (int r = 0; r < 4; ++r) {
                int row = wm + mt*16 + lq*4 + r;
                int col = n0 + wn + nt*16 + l16;
                atomicAdd(&C[(size_t)row*N + col], acc[mt][nt][r]);
            }
}

// ---------------- f32 SIMT GEMM for the Horner chain (K=128, L2-resident) ----------------
// C = Yin + (Dvec[col]*invn[0]) * (A[128][128] @ Bin[128][N])
__global__ __launch_bounds__(256) void gemm_horner(
    const float* __restrict__ A, const float* __restrict__ B,
    float* __restrict__ C, const float* __restrict__ Yin,
    const float* __restrict__ Dvec, const float* __restrict__ invn, int N)
{
    constexpr int BN = 64, TN = 4, BK = 16, TM = 8;
    __shared__ float As[BK][128];
    __shared__ float Bs[BK][BN];

    const int t = threadIdx.x;
    const int n0 = blockIdx.x * BN;
    const int tr = t / 16;                  // 0..15 -> rows tr*8..+7
    const int tc = t % 16;                  // 0..15 -> cols tc*4..

    float acc[TM][TN];
    #pragma unroll
    for (int i = 0; i < TM; ++i)
        #pragma unroll
        for (int j = 0; j < TN; ++j) acc[i][j] = 0.f;

    for (int k0 = 0; k0 < 128; k0 += BK) {
        #pragma unroll
        for (int it = 0; it < 2; ++it) {
            int flat = t + it*256;
            int m = flat >> 2, k4 = flat & 3;
            float4 v = *(const float4*)&A[(size_t)m*128 + k0 + k4*4];
            As[k4*4+0][m] = v.x; As[k4*4+1][m] = v.y;
            As[k4*4+2][m] = v.z; As[k4*4+3][m] = v.w;
        }
        {
            int kk = t / 16, n4 = t % 16;
            *(float4*)&Bs[kk][n4*4] = *(const float4*)&B[(size_t)(k0+kk)*N + n0 + n4*4];
        }
        __syncthreads();

        #pragma unroll
        for (int kk = 0; kk < BK; ++kk) {
            float a[TM], b[TN];
            #pragma unroll
            for (int i = 0; i < TM; i += 4)
                *(float4*)&a[i] = *(const float4*)&As[kk][tr*TM + i];
            #pragma unroll
            for (int j = 0; j < TN; j += 4)
                *(float4*)&b[j] = *(const float4*)&Bs[kk][tc*TN + j];
            #pragma unroll
            for (int i = 0; i < TM; ++i)
                #pragma unroll
                for (int j = 0; j < TN; ++j)
                    acc[i][j] = fmaf(a[i], b[j], acc[i][j]);
        }
        __syncthreads();
    }

    float inv0 = invn[0];
    float sc[TN];
    #pragma unroll
    for (int j = 0; j < TN; ++j) sc[j] = Dvec[n0 + tc*TN + j] * inv0;
    #pragma unroll
    for (int i = 0; i < TM; ++i) {
        int row = tr*TM + i;
        #pragma unroll
        for (int j = 0; j < TN; ++j) {
            int col = n0 + tc*TN + j;
            C[(size_t)row*N + col] = Yin[(size_t)row*N + col] + acc[i][j]*sc[j];
        }
    }
}

// ---------------- launch ----------------

extern "C" void kernel_launch(void* const* d_in, const int* in_sizes, int n_in,
                              void* d_out, int out_size, void* d_ws, size_t ws_size,
                              hipStream_t stream) {
    const float* X   = (const float*)d_in[0];   // 128 x 8192
    const float* F   = (const float*)d_in[1];   // 128 x 128
    const float* Q   = (const float*)d_in[2];   // 8192 x 8192
    const float* lam = (const float*)d_in[3];   // 8192
    const float* gam = (const float*)d_in[4];   // 1
    float* Z = (float*)d_out;                   // 128 x 8192 (f32)

    const int M = 128, N = 8192, K = 8192;

    char* ws = (char*)d_ws;
    float* FF  = (float*)(ws);                       // 64 KB
    float* inv = (float*)(ws + 65536);               // 4 B
    float* D   = (float*)(ws + 65792);               // 32 KB
    float* Y   = (float*)(ws + 131072);              // 4 MB
    float* RA  = (float*)(ws + 131072 + 4194304);    // 4 MB

    hipLaunchKernelGGL(kff,   dim3(128), dim3(128), 0, stream, F, FF);
    hipLaunchKernelGGL(knorm, dim3(1),   dim3(256), 0, stream, FF, inv);
    hipLaunchKernelGGL(kdvec, dim3(32),  dim3(256), 0, stream, lam, gam, D, N);

    // Y = X @ Q   (bf16 MFMA, split-K=8, atomic accumulate)
    hipMemsetAsync(Y, 0, (size_t)M*N*sizeof(float), stream);
    hipLaunchKernelGGL((gemm_mfma<false>), dim3(64, 8), dim3(256), 0, stream,
                       X, Q, Y, N, K, 1024);

    // Horner/Neumann: R <- Y + (D[j]*inv) * (FF @ R), 17 iterations (f32, L2-resident)
    float* RB = Z;
    const int KT = 17;
    for (int it = 0; it < KT; ++it) {
        const float* in = (it == 0) ? Y : ((it & 1) ? RA : RB);
        float* outp = (it & 1) ? RB : RA;
        hipLaunchKernelGGL(gemm_horner, dim3(128), dim3(256), 0, stream,
                           FF, in, outp, Y, D, inv, N);
    }

    // Z = RA @ Q^T  (bf16 MFMA, split-K=8, atomic accumulate)
    hipMemsetAsync(Z, 0, (size_t)M*N*sizeof(float), stream);
    hipLaunchKernelGGL((gemm_mfma<true>), dim3(64, 8), dim3(256), 0, stream,
                       RA, Q, Z, N, K, 1024);
}

// Round 3
// 185.985 us; speedup vs baseline: 5.9590x; 2.1148x over previous
//
#include <hip/hip_runtime.h>
#include <math.h>

#define EPS_F 1e-6f

typedef __attribute__((ext_vector_type(8))) short short8;
typedef __attribute__((ext_vector_type(4))) float f32x4;
typedef unsigned long long ull;

static __device__ __forceinline__ unsigned short f2bf(float f) {
    unsigned u = __float_as_uint(f);
    u += 0x7fff + ((u >> 16) & 1);          // round-to-nearest-even
    return (unsigned short)(u >> 16);
}
static __device__ __forceinline__ ull pack4(float a, float b, float c, float d) {
    return (ull)f2bf(a) | ((ull)f2bf(b) << 16) | ((ull)f2bf(c) << 32) | ((ull)f2bf(d) << 48);
}

// ---------------- small kernels ----------------

__global__ void kff(const float* __restrict__ F, float* __restrict__ FF) {
    int i = blockIdx.x, j = threadIdx.x;
    float s = 0.f;
    for (int k = 0; k < 128; ++k) s += F[k*128 + i] * F[k*128 + j];
    FF[i*128 + j] = s;
}

__global__ void knorm(const float* __restrict__ FF, float* __restrict__ inv) {
    float s = 0.f;
    for (int idx = threadIdx.x; idx < 128*128; idx += 256) { float v = FF[idx]; s += v*v; }
    for (int o = 32; o > 0; o >>= 1) s += __shfl_down(s, o);
    __shared__ float wsum[4];
    int lane = threadIdx.x & 63, w = threadIdx.x >> 6;
    if (lane == 0) wsum[w] = s;
    __syncthreads();
    if (threadIdx.x == 0) inv[0] = 1.f / (sqrtf(wsum[0]+wsum[1]+wsum[2]+wsum[3]) + EPS_F);
}

__global__ void kdvec(const float* __restrict__ lam, const float* __restrict__ gam,
                      float* __restrict__ D, int n) {
    int i = blockIdx.x*blockDim.x + threadIdx.x;
    if (i < n) D[i] = gam[0]*lam[i];
}

// ---------------- MFMA GEMM: C[128][N] += A[128][K] * op(B), bf16 inputs ----------------
template<bool TRANSB>
__global__ __launch_bounds__(256) void gemm_mfma(
    const float* __restrict__ A, const float* __restrict__ B,
    float* __restrict__ C, int N, int K, int kChunk)
{
    constexpr int LDT = 40;                 // shorts per LDS row: 32 data + 8 pad
    __shared__ short As[128 * LDT];
    __shared__ short Bs[128 * LDT];

    const int t    = threadIdx.x;
    const int lane = t & 63;
    const int w    = t >> 6;
    const int wm   = (w >> 1) * 64;
    const int wn   = (w & 1)  * 64;
    const int l16  = lane & 15;
    const int lq   = lane >> 4;
    const int n0   = blockIdx.x * 128;
    const int k_beg = blockIdx.y * kChunk;

    f32x4 acc[4][4];
    #pragma unroll
    for (int i = 0; i < 4; ++i)
        #pragma unroll
        for (int j = 0; j < 4; ++j) acc[i][j] = (f32x4){0.f,0.f,0.f,0.f};

    const int bn = t & 127, bkh = t >> 7;

    for (int k0 = k_beg; k0 < k_beg + kChunk; k0 += 32) {
        #pragma unroll
        for (int i = 0; i < 4; ++i) {
            int flat = t + i*256;
            int m = flat >> 3, k4 = flat & 7;
            float4 v = *(const float4*)&A[(size_t)m*K + k0 + k4*4];
            *(ull*)&As[m*LDT + k4*4] = pack4(v.x, v.y, v.z, v.w);
        }
        if (TRANSB) {
            #pragma unroll
            for (int i = 0; i < 4; ++i) {
                int flat = t + i*256;
                int n = flat >> 3, k4 = flat & 7;
                float4 v = *(const float4*)&B[(size_t)(n0+n)*K + k0 + k4*4];
                *(ull*)&Bs[n*LDT + k4*4] = pack4(v.x, v.y, v.z, v.w);
            }
        } else {
            float vv[16];
            #pragma unroll
            for (int j = 0; j < 16; ++j)
                vv[j] = B[(size_t)(k0 + bkh*16 + j)*N + n0 + bn];
            short8 p0, p1;
            #pragma unroll
            for (int j = 0; j < 8; ++j) { p0[j] = (short)f2bf(vv[j]); p1[j] = (short)f2bf(vv[j+8]); }
            *(short8*)&Bs[bn*LDT + bkh*16    ] = p0;
            *(short8*)&Bs[bn*LDT + bkh*16 + 8] = p1;
        }
        __syncthreads();

        short8 a[4], b[4];
        #pragma unroll
        for (int mt = 0; mt < 4; ++mt)
            a[mt] = *(const short8*)&As[(wm + mt*16 + l16)*LDT + lq*8];
        #pragma unroll
        for (int nt = 0; nt < 4; ++nt)
            b[nt] = *(const short8*)&Bs[(wn + nt*16 + l16)*LDT + lq*8];
        #pragma unroll
        for (int mt = 0; mt < 4; ++mt)
            #pragma unroll
            for (int nt = 0; nt < 4; ++nt)
                acc[mt][nt] = __builtin_amdgcn_mfma_f32_16x16x32_bf16(a[mt], b[nt], acc[mt][nt], 0, 0, 0);
        __syncthreads();
    }

    #pragma unroll
    for (int mt = 0; mt < 4; ++mt)
        #pragma unroll
        for (int nt = 0; nt < 4; ++nt)
            #pragma unroll
            for (int r = 0; r < 4; ++r) {
                int row = wm + mt*16 + lq*4 + r;
                int col = n0 + wn + nt*16 + l16;
                atomicAdd(&C[(size_t)row*N + col], acc[mt][nt][r]);
            }
}

// ---------------- fused Horner: R = sum_{p=0..T} (s_j A)^p y_j, all iterations in LDS ----
// A = FF (bf16 in LDS), s_j = D[j]*inv. Block owns 32 columns; 8 waves (512 thr).
__global__ __launch_bounds__(512) void horner_fused(
    const float* __restrict__ FF, const float* __restrict__ invn,
    const float* __restrict__ D, const float* __restrict__ Y,
    float* __restrict__ R, int N)
{
    constexpr int LDT = 136;                // 128 data + 8 pad shorts
    constexpr int T = 14;
    __shared__ short Abf[128 * LDT];        // [m][k] k-contiguous
    __shared__ short Rbf[32 * LDT];         // [j_local][m] m-contiguous

    const int t    = threadIdx.x;
    const int lane = t & 63;
    const int w    = t >> 6;                // 0..7
    const int wm   = (w >> 1) * 32;         // row quarter: 0/32/64/96
    const int wn   = (w & 1) * 16;          // col half: 0/16
    const int l16  = lane & 15;
    const int lq   = lane >> 4;
    const int j0   = blockIdx.x * 32;

    // stage A = bf16(FF): 4096 float4 over 512 threads
    #pragma unroll
    for (int i = 0; i < 8; ++i) {
        int flat = t + i*512;
        int m = flat >> 5, k4 = flat & 31;
        float4 v = *(const float4*)&FF[m*128 + k4*4];
        *(ull*)&Abf[m*LDT + k4*4] = pack4(v.x, v.y, v.z, v.w);
    }
    // stage Rbf = bf16(Y[:, j0..j0+31])  (transposed: Rbf[j][m])
    {
        int j = t & 31, mg = t >> 5;        // mg 0..15, rows mg*8..+7
        float vv[8];
        #pragma unroll
        for (int r2 = 0; r2 < 8; ++r2)
            vv[r2] = Y[(size_t)(mg*8 + r2)*N + j0 + j];
        *(ull*)&Rbf[j*LDT + mg*8    ] = pack4(vv[0], vv[1], vv[2], vv[3]);
        *(ull*)&Rbf[j*LDT + mg*8 + 4] = pack4(vv[4], vv[5], vv[6], vv[7]);
    }
    // Y in C-fragment registers; per-column scale
    const int col = j0 + wn + l16;
    float yreg[2][4];
    #pragma unroll
    for (int mt = 0; mt < 2; ++mt)
        #pragma unroll
        for (int r = 0; r < 4; ++r)
            yreg[mt][r] = Y[(size_t)(wm + mt*16 + lq*4 + r)*N + col];
    const float s = D[col] * invn[0];

    for (int it = 0; it < T; ++it) {
        __syncthreads();                    // Rbf ready
        f32x4 racc[2];
        racc[0] = (f32x4){0.f,0.f,0.f,0.f};
        racc[1] = (f32x4){0.f,0.f,0.f,0.f};
        #pragma unroll
        for (int kq = 0; kq < 4; ++kq) {
            short8 b  = *(const short8*)&Rbf[(wn + l16)*LDT + kq*32 + lq*8];
            short8 a0 = *(const short8*)&Abf[(wm      + l16)*LDT + kq*32 + lq*8];
            short8 a1 = *(const short8*)&Abf[(wm + 16 + l16)*LDT + kq*32 + lq*8];
            racc[0] = __builtin_amdgcn_mfma_f32_16x16x32_bf16(a0, b, racc[0], 0, 0, 0);
            racc[1] = __builtin_amdgcn_mfma_f32_16x16x32_bf16(a1, b, racc[1], 0, 0, 0);
        }
        __syncthreads();                    // reads done before overwrite
        #pragma unroll
        for (int mt = 0; mt < 2; ++mt) {
            float r0 = yreg[mt][0] + s*racc[mt][0];
            float r1 = yreg[mt][1] + s*racc[mt][1];
            float r2 = yreg[mt][2] + s*racc[mt][2];
            float r3 = yreg[mt][3] + s*racc[mt][3];
            if (it < T-1) {
                *(ull*)&Rbf[(wn + l16)*LDT + wm + mt*16 + lq*4] = pack4(r0, r1, r2, r3);
            } else {
                int row = wm + mt*16 + lq*4;
                R[(size_t)(row+0)*N + col] = r0;
                R[(size_t)(row+1)*N + col] = r1;
                R[(size_t)(row+2)*N + col] = r2;
                R[(size_t)(row+3)*N + col] = r3;
            }
        }
    }
}

// ---------------- launch ----------------

extern "C" void kernel_launch(void* const* d_in, const int* in_sizes, int n_in,
                              void* d_out, int out_size, void* d_ws, size_t ws_size,
                              hipStream_t stream) {
    const float* X   = (const float*)d_in[0];   // 128 x 8192
    const float* F   = (const float*)d_in[1];   // 128 x 128
    const float* Q   = (const float*)d_in[2];   // 8192 x 8192
    const float* lam = (const float*)d_in[3];   // 8192
    const float* gam = (const float*)d_in[4];   // 1
    float* Z = (float*)d_out;                   // 128 x 8192 (f32)

    const int M = 128, N = 8192, K = 8192;

    char* ws = (char*)d_ws;
    float* FF  = (float*)(ws);                       // 64 KB
    float* inv = (float*)(ws + 65536);               // 4 B
    float* D   = (float*)(ws + 65792);               // 32 KB
    float* Y   = (float*)(ws + 131072);              // 4 MB
    float* RA  = (float*)(ws + 131072 + 4194304);    // 4 MB

    hipLaunchKernelGGL(kff,   dim3(128), dim3(128), 0, stream, F, FF);
    hipLaunchKernelGGL(knorm, dim3(1),   dim3(256), 0, stream, FF, inv);
    hipLaunchKernelGGL(kdvec, dim3(32),  dim3(256), 0, stream, lam, gam, D, N);

    // Y = X @ Q   (bf16 MFMA, split-K=8, atomic accumulate)
    hipMemsetAsync(Y, 0, (size_t)M*N*sizeof(float), stream);
    hipLaunchKernelGGL((gemm_mfma<false>), dim3(64, 8), dim3(256), 0, stream,
                       X, Q, Y, N, K, 1024);

    // fused Horner chain: R = truncated Neumann series applied to Y (one kernel)
    hipLaunchKernelGGL(horner_fused, dim3(256), dim3(512), 0, stream,
                       FF, inv, D, Y, RA, N);

    // Z = RA @ Q^T  (bf16 MFMA, split-K=8, atomic accumulate)
    hipMemsetAsync(Z, 0, (size_t)M*N*sizeof(float), stream);
    hipLaunchKernelGGL((gemm_mfma<true>), dim3(64, 8), dim3(256), 0, stream,
                       RA, Q, Z, N, K, 1024);
}